// Round 1
// baseline (1012.788 us; speedup 1.0000x reference)
//
#include <hip/hip_runtime.h>

#define NN   50000
#define EE   800000
#define DDIN 128
#define HH   3
#define FF   64
#define HF   192
#define NEG  0.2f

__device__ __forceinline__ float wave_max(float v){
  #pragma unroll
  for (int off = 32; off; off >>= 1) v = fmaxf(v, __shfl_xor(v, off));
  return v;
}
__device__ __forceinline__ float wave_sum(float v){
  #pragma unroll
  for (int off = 32; off; off >>= 1) v += __shfl_xor(v, off);
  return v;
}

// ---------------- CSR build (dst-grouped), shared by both layers ----------------
__global__ __launch_bounds__(256) void count_kernel(const int* __restrict__ dst,
                                                    int* __restrict__ counts){
  int e = blockIdx.x * 256 + threadIdx.x;
  if (e < EE) atomicAdd(&counts[dst[e]], 1);
}

__global__ __launch_bounds__(1024) void scan_kernel(const int* __restrict__ counts,
                                                    int* __restrict__ row_ptr, int n){
  __shared__ int sh[1024];
  __shared__ int carry_sh;
  if (threadIdx.x == 0) carry_sh = 0;
  __syncthreads();
  for (int base = 0; base < n; base += 1024){
    int i = base + (int)threadIdx.x;
    int v = (i < n) ? counts[i] : 0;
    sh[threadIdx.x] = v;
    __syncthreads();
    for (int off = 1; off < 1024; off <<= 1){
      int t = (threadIdx.x >= (unsigned)off) ? sh[threadIdx.x - off] : 0;
      __syncthreads();
      sh[threadIdx.x] += t;
      __syncthreads();
    }
    int incl  = sh[threadIdx.x];
    int carry = carry_sh;
    if (i < n) row_ptr[i + 1] = carry + incl;
    __syncthreads();
    if (threadIdx.x == 1023) carry_sh = carry + sh[1023];
    __syncthreads();
  }
  if (threadIdx.x == 0) row_ptr[0] = 0;
}

__global__ __launch_bounds__(256) void scatter_kernel(const int* __restrict__ dst,
                                                      const int* __restrict__ row_ptr,
                                                      int* __restrict__ cursor,
                                                      int* __restrict__ eid){
  int e = blockIdx.x * 256 + threadIdx.x;
  if (e >= EE) return;
  int d = dst[e];
  int pos = atomicAdd(&cursor[d], 1);
  eid[row_ptr[d] + pos] = e;
}

// ---------------- out0 = feats copy ----------------
__global__ __launch_bounds__(256) void copy4_kernel(const float4* __restrict__ in,
                                                    float4* __restrict__ out, int n){
  int i = blockIdx.x * 256 + threadIdx.x;
  if (i < n) out[i] = in[i];
}

// ---------------- fp32 tiled GEMM: C[M,N] = A[M,K] @ B[K,N] + bias[N] ----------------
__global__ __launch_bounds__(256) void gemm_bias(const float* __restrict__ A,
                                                 const float* __restrict__ B,
                                                 const float* __restrict__ bias,
                                                 float* __restrict__ C,
                                                 int M, int N, int K){
  __shared__ float As[16][65];
  __shared__ float Bs[16][64];
  int tx = threadIdx.x;
  int brow = blockIdx.x * 64, bcol = blockIdx.y * 64;
  int tc = (tx & 15) * 4, tr = (tx >> 4) * 4;
  float acc[4][4] = {};
  for (int k0 = 0; k0 < K; k0 += 16){
    #pragma unroll
    for (int l = tx; l < 64 * 16; l += 256){
      int r = l >> 4, c = l & 15;
      int gr = brow + r;
      As[c][r] = (gr < M) ? A[(size_t)gr * K + k0 + c] : 0.f;
    }
    #pragma unroll
    for (int l = tx; l < 16 * 64; l += 256){
      int r = l >> 6, c = l & 63;
      Bs[r][c] = B[(size_t)(k0 + r) * N + bcol + c];
    }
    __syncthreads();
    #pragma unroll
    for (int kk = 0; kk < 16; kk++){
      float a0 = As[kk][tr], a1 = As[kk][tr + 1], a2 = As[kk][tr + 2], a3 = As[kk][tr + 3];
      float b0 = Bs[kk][tc], b1 = Bs[kk][tc + 1], b2 = Bs[kk][tc + 2], b3 = Bs[kk][tc + 3];
      acc[0][0] += a0 * b0; acc[0][1] += a0 * b1; acc[0][2] += a0 * b2; acc[0][3] += a0 * b3;
      acc[1][0] += a1 * b0; acc[1][1] += a1 * b1; acc[1][2] += a1 * b2; acc[1][3] += a1 * b3;
      acc[2][0] += a2 * b0; acc[2][1] += a2 * b1; acc[2][2] += a2 * b2; acc[2][3] += a2 * b3;
      acc[3][0] += a3 * b0; acc[3][1] += a3 * b1; acc[3][2] += a3 * b2; acc[3][3] += a3 * b3;
    }
    __syncthreads();
  }
  #pragma unroll
  for (int i = 0; i < 4; i++){
    int gr = brow + tr + i;
    if (gr >= M) continue;
    float* cp = C + (size_t)gr * N + bcol + tc;
    #pragma unroll
    for (int j = 0; j < 4; j++) cp[j] = acc[i][j] + bias[bcol + tc + j];
  }
}

// ---------------- per-edge attention logits: one wave per edge ----------------
__global__ __launch_bounds__(256) void edge_logits_kernel(const float* __restrict__ fs,
                                                          const float* __restrict__ fd,
                                                          const int* __restrict__ src,
                                                          const int* __restrict__ dst,
                                                          const float* __restrict__ attn,
                                                          float* __restrict__ logits){
  int wid  = (blockIdx.x * 256 + (int)threadIdx.x) >> 6;
  int lane = threadIdx.x & 63;
  if (wid >= EE) return;
  int s = src[wid], d = dst[wid];
  const float* fsr = fs + (size_t)s * HF;
  const float* fdr = fd + (size_t)d * HF;
  float r[HH];
  #pragma unroll
  for (int h = 0; h < HH; h++){
    float x = fsr[h * 64 + lane] + fdr[h * 64 + lane];
    x = x > 0.f ? x : NEG * x;
    r[h] = wave_sum(x * attn[h * 64 + lane]);
  }
  if (lane == 0){
    float* lp = logits + 3 * (size_t)wid;
    lp[0] = r[0]; lp[1] = r[1]; lp[2] = r[2];
  }
}

// ---------------- per-node softmax + weighted aggregation: one wave per node ----------------
__global__ __launch_bounds__(256) void node_agg_kernel(const float* __restrict__ fs,
                                                       const float* __restrict__ logits,
                                                       const int* __restrict__ row_ptr,
                                                       const int* __restrict__ eid,
                                                       const int* __restrict__ src,
                                                       const float* __restrict__ bias,
                                                       float* __restrict__ out){
  int node = (blockIdx.x * 256 + (int)threadIdx.x) >> 6;
  int lane = threadIdx.x & 63;
  if (node >= NN) return;
  int r0 = row_ptr[node];
  int deg = row_ptr[node + 1] - r0;

  float m0 = -1e30f, m1 = -1e30f, m2 = -1e30f;
  for (int i = lane; i < deg; i += 64){
    int e = eid[r0 + i];
    const float* lp = logits + 3 * (size_t)e;
    m0 = fmaxf(m0, lp[0]); m1 = fmaxf(m1, lp[1]); m2 = fmaxf(m2, lp[2]);
  }
  m0 = wave_max(m0); m1 = wave_max(m1); m2 = wave_max(m2);

  float s0 = 0.f, s1 = 0.f, s2 = 0.f;
  for (int i = lane; i < deg; i += 64){
    int e = eid[r0 + i];
    const float* lp = logits + 3 * (size_t)e;
    s0 += __expf(lp[0] - m0); s1 += __expf(lp[1] - m1); s2 += __expf(lp[2] - m2);
  }
  s0 = wave_sum(s0); s1 = wave_sum(s1); s2 = wave_sum(s2);
  float i0 = deg ? 1.f / s0 : 0.f;
  float i1 = deg ? 1.f / s1 : 0.f;
  float i2 = deg ? 1.f / s2 : 0.f;

  float a0 = 0.f, a1 = 0.f, a2 = 0.f;
  for (int base = 0; base < deg; base += 64){
    int cnt = min(64, deg - base);
    int sn = 0; float w0 = 0.f, w1 = 0.f, w2 = 0.f;
    if (lane < cnt){
      int e = eid[r0 + base + lane];
      sn = src[e];
      const float* lp = logits + 3 * (size_t)e;
      w0 = __expf(lp[0] - m0) * i0;
      w1 = __expf(lp[1] - m1) * i1;
      w2 = __expf(lp[2] - m2) * i2;
    }
    for (int j = 0; j < cnt; j++){
      int snj  = __shfl(sn, j);
      float c0 = __shfl(w0, j), c1 = __shfl(w1, j), c2 = __shfl(w2, j);
      const float* fr = fs + (size_t)snj * HF;
      a0 += c0 * fr[lane];
      a1 += c1 * fr[64 + lane];
      a2 += c2 * fr[128 + lane];
    }
  }
  size_t o = (size_t)node * HF;
  out[o + lane]       = tanhf(a0 + bias[lane]);
  out[o + 64 + lane]  = tanhf(a1 + bias[64 + lane]);
  out[o + 128 + lane] = tanhf(a2 + bias[128 + lane]);
}

extern "C" void kernel_launch(void* const* d_in, const int* in_sizes, int n_in,
                              void* d_out, int out_size, void* d_ws, size_t ws_size,
                              hipStream_t stream) {
  const float* feats = (const float*)d_in[0];
  const int*   src   = (const int*)d_in[1];
  const int*   dst   = (const int*)d_in[2];
  const float* W1s = (const float*)d_in[3];  const float* b1s   = (const float*)d_in[4];
  const float* W1d = (const float*)d_in[5];  const float* b1d   = (const float*)d_in[6];
  const float* at1 = (const float*)d_in[7];  const float* bias1 = (const float*)d_in[8];
  const float* W2s = (const float*)d_in[9];  const float* b2s   = (const float*)d_in[10];
  const float* W2d = (const float*)d_in[11]; const float* b2d   = (const float*)d_in[12];
  const float* at2 = (const float*)d_in[13]; const float* bias2 = (const float*)d_in[14];

  float* out  = (float*)d_out;
  float* out1 = out  + (size_t)NN * DDIN;
  float* out2 = out1 + (size_t)NN * HF;

  float* fs     = (float*)d_ws;                 // NN*HF
  float* fd     = fs + (size_t)NN * HF;         // NN*HF
  float* logits = fd + (size_t)NN * HF;         // EE*3
  int*   counts  = (int*)(logits + (size_t)EE * 3);  // NN
  int*   row_ptr = counts + NN;                      // NN+1
  int*   eid     = row_ptr + NN + 1;                 // EE

  // CSR build (dst-grouped), shared by both layers
  hipMemsetAsync(counts, 0, NN * sizeof(int), stream);
  count_kernel<<<(EE + 255) / 256, 256, 0, stream>>>(dst, counts);
  scan_kernel<<<1, 1024, 0, stream>>>(counts, row_ptr, NN);
  hipMemsetAsync(counts, 0, NN * sizeof(int), stream);
  scatter_kernel<<<(EE + 255) / 256, 256, 0, stream>>>(dst, row_ptr, counts, eid);

  // out0 = feats
  copy4_kernel<<<(NN * DDIN / 4 + 255) / 256, 256, 0, stream>>>(
      (const float4*)feats, (float4*)out, NN * DDIN / 4);

  dim3 gemm_grid1((NN + 63) / 64, HF / 64);

  // layer 1
  gemm_bias<<<gemm_grid1, 256, 0, stream>>>(feats, W1s, b1s, fs, NN, HF, DDIN);
  gemm_bias<<<gemm_grid1, 256, 0, stream>>>(feats, W1d, b1d, fd, NN, HF, DDIN);
  edge_logits_kernel<<<EE / 4, 256, 0, stream>>>(fs, fd, src, dst, at1, logits);
  node_agg_kernel<<<(NN + 3) / 4, 256, 0, stream>>>(fs, logits, row_ptr, eid, src, bias1, out1);

  // layer 2 (input = out1, K = HF)
  gemm_bias<<<gemm_grid1, 256, 0, stream>>>(out1, W2s, b2s, fs, NN, HF, HF);
  gemm_bias<<<gemm_grid1, 256, 0, stream>>>(out1, W2d, b2d, fd, NN, HF, HF);
  edge_logits_kernel<<<EE / 4, 256, 0, stream>>>(fs, fd, src, dst, at2, logits);
  node_agg_kernel<<<(NN + 3) / 4, 256, 0, stream>>>(fs, logits, row_ptr, eid, src, bias2, out2);
}